// Round 10
// baseline (578.439 us; speedup 1.0000x reference)
//
#include <hip/hip_runtime.h>
#include <hip/hip_bf16.h>
#include <math.h>

#define V 32000
#define T 128
#define B 64
#define E 32
#define H 8
#define TB (T*B)   // 8192

#define NSL 40     // col slices of 800
#define TPW 50     // 16-col tiles per slice
#define RG 4       // row-groups per wave (64 rows)
#define RPW (RG*16)        // 64 rows per wave
#define RPBK (RPW*4)       // 256 rows per block (4 waves, same slice)

typedef short bf16x8 __attribute__((ext_vector_type(8)));
typedef float f32x4  __attribute__((ext_vector_type(4)));

// ---------------- params struct ----------------
struct P1 {
  const int* x; const float* emb;
  const float* Wf1; const float* bf1; const float* Wi1; const float* bi1;
  const float* WC1; const float* bC1; const float* Wo1; const float* bo1;
  const float* Wf2; const float* bf2; const float* Wi2; const float* bi2;
  const float* WC2; const float* bC2; const float* Wo2; const float* bo2;
};

__device__ __forceinline__ float sigm_f(float x) { return 1.f / (1.f + __expf(-x)); }
__device__ __forceinline__ float tanh_f(float x) { float e = __expf(2.f * x); return 1.f - 2.f / (e + 1.f); }
__device__ __forceinline__ ushort f2bf(float f) {            // RNE fp32->bf16
  unsigned u = __float_as_uint(f);
  u = (u + 0x7FFFu + ((u >> 16) & 1u)) >> 16;
  return (ushort)u;
}

// ---------------- kernel 1: embed + e-part projections (bias folded in) ----------------
__global__ __launch_bounds__(256) void k_embed(P1 p, float* __restrict__ pe) {
  int r = blockIdx.x * 256 + threadIdx.x;
  int idx = p.x[r];
  const float* e = p.emb + (long)idx * E;
  float ev[E];
  #pragma unroll
  for (int k = 0; k < E; k += 4) {
    float4 v4 = *(const float4*)(e + k);
    ev[k] = v4.x; ev[k+1] = v4.y; ev[k+2] = v4.z; ev[k+3] = v4.w;
  }
  #pragma unroll
  for (int d = 0; d < 2; ++d) {
    const float* Wf = d ? p.Wf2 : p.Wf1;
    const float* Wi = d ? p.Wi2 : p.Wi1;
    const float* Wo = d ? p.Wo2 : p.Wo1;
    const float* WC = d ? p.WC2 : p.WC1;
    const float* bC = d ? p.bC2 : p.bC1;
    float af = (d ? p.bf2 : p.bf1)[0];
    float ai = (d ? p.bi2 : p.bi1)[0];
    float ao = (d ? p.bo2 : p.bo1)[0];
    float ac[H];
    #pragma unroll
    for (int j = 0; j < H; ++j) ac[j] = bC[j];
    #pragma unroll
    for (int k = 0; k < E; ++k) {
      float ek = ev[k];
      af += ek * Wf[8 + k];
      ai += ek * Wi[8 + k];
      ao += ek * Wo[8 + k];
      #pragma unroll
      for (int j = 0; j < H; ++j) ac[j] += ek * WC[(8 + k) * H + j];
    }
    float* ped = pe + d * 11 * TB;
    ped[0 * TB + r] = af;
    ped[1 * TB + r] = ai;
    ped[2 * TB + r] = ao;
    #pragma unroll
    for (int j = 0; j < H; ++j) ped[(3 + j) * TB + r] = ac[j];
  }
}

// ---------------- kernel 2: sequential LSTM; writes bf16 thbf[TB][32] directly -------
// dir0 owns halves k=[0..7] and pad [16..23]; dir1 owns [8..15] and pad [24..31].
__global__ __launch_bounds__(64) void k_lstm(P1 p, const float* __restrict__ pe,
                                             ushort* __restrict__ thbf) {
  int dir = blockIdx.x;
  int lane = threadIdx.x;
  const float* Wf = dir ? p.Wf2 : p.Wf1;
  const float* Wi = dir ? p.Wi2 : p.Wi1;
  const float* Wo = dir ? p.Wo2 : p.Wo1;
  const float* WC = dir ? p.WC2 : p.WC1;
  float wf[8], wi[8], wo[8], wc[8][8];
  #pragma unroll
  for (int k = 0; k < 8; ++k) { wf[k] = Wf[k]; wi[k] = Wi[k]; wo[k] = Wo[k]; }
  #pragma unroll
  for (int k = 0; k < 8; ++k)
    #pragma unroll
    for (int j = 0; j < 8; ++j) wc[k][j] = WC[k * H + j];

  float h[8], C[8];
  #pragma unroll
  for (int j = 0; j < 8; ++j) { h[j] = 0.f; C[j] = 0.f; }

  const float* ped = pe + dir * 11 * TB;

  int tf = dir ? (T - 1) : 0;
  int rf = tf * B + lane;
  float nf = ped[0 * TB + rf], ni = ped[1 * TB + rf], no_ = ped[2 * TB + rf];
  float nc[8];
  #pragma unroll
  for (int j = 0; j < 8; ++j) nc[j] = ped[(3 + j) * TB + rf];

  ushort zed[8] = {0,0,0,0,0,0,0,0};

  for (int s = 0; s < T; ++s) {
    int t = dir ? (T - 1 - s) : s;
    int r = t * B + lane;
    float af = nf, ai = ni, ao = no_;
    float ac[8];
    #pragma unroll
    for (int j = 0; j < 8; ++j) ac[j] = nc[j];

    if (s + 1 < T) {
      int t2 = dir ? (T - 2 - s) : (s + 1);
      int r2 = t2 * B + lane;
      nf = ped[0 * TB + r2]; ni = ped[1 * TB + r2]; no_ = ped[2 * TB + r2];
      #pragma unroll
      for (int j = 0; j < 8; ++j) nc[j] = ped[(3 + j) * TB + r2];
    }

    // record pre-update h (carry-in) as bf16
    ushort hb[8];
    #pragma unroll
    for (int j = 0; j < 8; ++j) hb[j] = f2bf(h[j]);
    *(bf16x8*)(thbf + (long)r * 32 + dir * 8)        = *(bf16x8*)hb;   // K halves
    *(bf16x8*)(thbf + (long)r * 32 + 16 + dir * 8)   = *(bf16x8*)zed;  // zero pad

    #pragma unroll
    for (int k = 0; k < 8; ++k) {
      float hk = h[k];
      af += hk * wf[k];
      ai += hk * wi[k];
      ao += hk * wo[k];
      #pragma unroll
      for (int j = 0; j < 8; ++j) ac[j] += hk * wc[k][j];
    }
    float f = sigm_f(af), i = sigm_f(ai), o = sigm_f(ao);
    #pragma unroll
    for (int j = 0; j < 8; ++j) {
      float Cn = f * C[j] + i + tanh_f(ac[j]);
      C[j] = Cn;
      h[j] = o * tanh_f(Cn);
    }
  }
}

// ---------------- prep: Wout fp32 [16][V] -> Wbf bf16 [V][32] (K padded) ------------
__global__ __launch_bounds__(256) void k_cvtW(const float* __restrict__ Wout,
                                              ushort* __restrict__ Wbf) {
  int c = blockIdx.x * 256 + threadIdx.x;
  ushort tmp[32];
  #pragma unroll
  for (int k = 0; k < 16; ++k) tmp[k] = f2bf(Wout[k * V + c]);
  #pragma unroll
  for (int k = 16; k < 32; ++k) tmp[k] = 0;
  #pragma unroll
  for (int i = 0; i < 4; ++i)
    *(bf16x8*)(Wbf + (long)c * 32 + i * 8) = *(bf16x8*)(tmp + i * 8);
}

// ---------------- pass 1 (MFMA): per-slice sumexp; wave = 64 rows x 800 cols --------
// grid (NSL, TB/RPBK); block = 4 waves, SAME slice, different 64-row chunks.
__global__ __launch_bounds__(256) void k_sum(const ushort* __restrict__ thbf,
                                             const ushort* __restrict__ Wbf,
                                             const float* __restrict__ bout,
                                             float* __restrict__ pms) {
  int tid = threadIdx.x;
  int wv = tid >> 6, l = tid & 63;
  int slice = blockIdx.x;
  int rbase = blockIdx.y * RPBK + wv * RPW;
  int cbase = slice * (TPW * 16);

  bf16x8 A[RG];
  #pragma unroll
  for (int g = 0; g < RG; ++g)
    A[g] = *(const bf16x8*)(thbf + (long)(rbase + g * 16 + (l & 15)) * 32 + (l >> 4) * 8);

  float racc[RG][4];
  #pragma unroll
  for (int g = 0; g < RG; ++g)
    #pragma unroll
    for (int j = 0; j < 4; ++j) racc[g][j] = 0.f;

  for (int t = 0; t < TPW; ++t) {
    int c = cbase + t * 16 + (l & 15);
    bf16x8 Bf = *(const bf16x8*)(Wbf + (long)c * 32 + (l >> 4) * 8);
    float bb = bout[c];
    #pragma unroll
    for (int g = 0; g < RG; ++g) {
      f32x4 acc = {0.f, 0.f, 0.f, 0.f};
      acc = __builtin_amdgcn_mfma_f32_16x16x32_bf16(A[g], Bf, acc, 0, 0, 0);
      racc[g][0] += __expf(acc[0] + bb);
      racc[g][1] += __expf(acc[1] + bb);
      racc[g][2] += __expf(acc[2] + bb);
      racc[g][3] += __expf(acc[3] + bb);
    }
  }

  #pragma unroll
  for (int g = 0; g < RG; ++g)
    #pragma unroll
    for (int j = 0; j < 4; ++j) {
      float s = racc[g][j];
      s += __shfl_xor(s, 1); s += __shfl_xor(s, 2);
      s += __shfl_xor(s, 4); s += __shfl_xor(s, 8);
      if ((l & 15) == 0)
        pms[(long)(rbase + g * 16 + (l >> 4) * 4 + j) * NSL + slice] = s;
    }
}

// ---------------- Z = log(sum of partials) ----------------
__global__ __launch_bounds__(256) void k_reduce(const float* __restrict__ pms, float* __restrict__ Z) {
  int r = blockIdx.x * 256 + threadIdx.x;
  float s = 0.f;
  #pragma unroll
  for (int i = 0; i < NSL; ++i) s += pms[(long)r * NSL + i];
  Z[r] = logf(s);
}

// ---------------- pass 2 (MFMA): logits + b - Z -> out; wave = 64 rows x 800 cols ---
__global__ __launch_bounds__(256) void k_wr(const ushort* __restrict__ thbf,
                                            const ushort* __restrict__ Wbf,
                                            const float* __restrict__ bout,
                                            const float* __restrict__ Z,
                                            float* __restrict__ out) {
  int tid = threadIdx.x;
  int wv = tid >> 6, l = tid & 63;
  int slice = blockIdx.x;
  int rbase = blockIdx.y * RPBK + wv * RPW;
  int cbase = slice * (TPW * 16);

  bf16x8 A[RG];
  float Zv[RG][4];
  #pragma unroll
  for (int g = 0; g < RG; ++g) {
    A[g] = *(const bf16x8*)(thbf + (long)(rbase + g * 16 + (l & 15)) * 32 + (l >> 4) * 8);
    #pragma unroll
    for (int j = 0; j < 4; ++j)
      Zv[g][j] = Z[rbase + g * 16 + (l >> 4) * 4 + j];
  }

  for (int t = 0; t < TPW; ++t) {
    int c = cbase + t * 16 + (l & 15);
    bf16x8 Bf = *(const bf16x8*)(Wbf + (long)c * 32 + (l >> 4) * 8);
    float bb = bout[c];
    #pragma unroll
    for (int g = 0; g < RG; ++g) {
      f32x4 acc = {0.f, 0.f, 0.f, 0.f};
      acc = __builtin_amdgcn_mfma_f32_16x16x32_bf16(A[g], Bf, acc, 0, 0, 0);
      #pragma unroll
      for (int j = 0; j < 4; ++j)
        out[(long)(rbase + g * 16 + (l >> 4) * 4 + j) * V + c] = acc[j] + bb - Zv[g][j];
    }
  }
}

extern "C" void kernel_launch(void* const* d_in, const int* in_sizes, int n_in,
                              void* d_out, int out_size, void* d_ws, size_t ws_size,
                              hipStream_t stream) {
  (void)in_sizes; (void)n_in; (void)out_size; (void)ws_size;
  P1 p;
  p.x   = (const int*)  d_in[0];
  p.emb = (const float*)d_in[1];
  p.Wf1 = (const float*)d_in[2];  p.bf1 = (const float*)d_in[3];
  p.Wi1 = (const float*)d_in[4];  p.bi1 = (const float*)d_in[5];
  p.WC1 = (const float*)d_in[6];  p.bC1 = (const float*)d_in[7];
  p.Wo1 = (const float*)d_in[8];  p.bo1 = (const float*)d_in[9];
  p.Wf2 = (const float*)d_in[10]; p.bf2 = (const float*)d_in[11];
  p.Wi2 = (const float*)d_in[12]; p.bi2 = (const float*)d_in[13];
  p.WC2 = (const float*)d_in[14]; p.bC2 = (const float*)d_in[15];
  p.Wo2 = (const float*)d_in[16]; p.bo2 = (const float*)d_in[17];
  const float* Wout = (const float*)d_in[18];
  const float* bout = (const float*)d_in[19];

  float*  pe   = (float*)d_ws;                     // 180224 f
  float*  pms  = pe + 2 * 11 * TB;                 // TB*NSL = 327680 f
  float*  Zr   = pms + (long)TB * NSL;             // 8192 f
  ushort* thbf = (ushort*)(Zr + TB);               // TB*32 ushort
  ushort* Wbf  = thbf + (long)TB * 32;             // V*32 ushort

  float* out = (float*)d_out;

  k_embed <<<dim3(TB / 256),       dim3(256), 0, stream>>>(p, pe);
  k_cvtW  <<<dim3(V / 256),        dim3(256), 0, stream>>>(Wout, Wbf);
  k_lstm  <<<dim3(2),              dim3(64),  0, stream>>>(p, pe, thbf);
  k_sum   <<<dim3(NSL, TB / RPBK), dim3(256), 0, stream>>>(thbf, Wbf, bout, pms);
  k_reduce<<<dim3(TB / 256),       dim3(256), 0, stream>>>(pms, Zr);
  k_wr    <<<dim3(NSL, TB / RPBK), dim3(256), 0, stream>>>(thbf, Wbf, bout, Zr, out);
}

// Round 11
// 554.401 us; speedup vs baseline: 1.0434x; 1.0434x over previous
//
#include <hip/hip_runtime.h>
#include <hip/hip_bf16.h>
#include <math.h>

#define V 32000
#define T 128
#define B 64
#define E 32
#define H 8
#define TB (T*B)   // 8192

#define NSL 40     // col slices of 800
#define TPW 50     // 16-col tiles per slice

typedef short bf16x8 __attribute__((ext_vector_type(8)));
typedef float f32x4  __attribute__((ext_vector_type(4)));

// ---------------- params struct ----------------
struct P1 {
  const int* x; const float* emb;
  const float* Wf1; const float* bf1; const float* Wi1; const float* bi1;
  const float* WC1; const float* bC1; const float* Wo1; const float* bo1;
  const float* Wf2; const float* bf2; const float* Wi2; const float* bi2;
  const float* WC2; const float* bC2; const float* Wo2; const float* bo2;
};

__device__ __forceinline__ float sigm_f(float x) { return 1.f / (1.f + __expf(-x)); }
__device__ __forceinline__ float tanh_f(float x) { float e = __expf(2.f * x); return 1.f - 2.f / (e + 1.f); }
__device__ __forceinline__ ushort f2bf(float f) {            // RNE fp32->bf16
  unsigned u = __float_as_uint(f);
  u = (u + 0x7FFFu + ((u >> 16) & 1u)) >> 16;
  return (ushort)u;
}

// ---------------- kernel 1: embed + e-part projections (bias folded in) ----------------
__global__ __launch_bounds__(256) void k_embed(P1 p, float* __restrict__ pe) {
  int r = blockIdx.x * 256 + threadIdx.x;
  int idx = p.x[r];
  const float* e = p.emb + (long)idx * E;
  float ev[E];
  #pragma unroll
  for (int k = 0; k < E; k += 4) {
    float4 v4 = *(const float4*)(e + k);
    ev[k] = v4.x; ev[k+1] = v4.y; ev[k+2] = v4.z; ev[k+3] = v4.w;
  }
  #pragma unroll
  for (int d = 0; d < 2; ++d) {
    const float* Wf = d ? p.Wf2 : p.Wf1;
    const float* Wi = d ? p.Wi2 : p.Wi1;
    const float* Wo = d ? p.Wo2 : p.Wo1;
    const float* WC = d ? p.WC2 : p.WC1;
    const float* bC = d ? p.bC2 : p.bC1;
    float af = (d ? p.bf2 : p.bf1)[0];
    float ai = (d ? p.bi2 : p.bi1)[0];
    float ao = (d ? p.bo2 : p.bo1)[0];
    float ac[H];
    #pragma unroll
    for (int j = 0; j < H; ++j) ac[j] = bC[j];
    #pragma unroll
    for (int k = 0; k < E; ++k) {
      float ek = ev[k];
      af += ek * Wf[8 + k];
      ai += ek * Wi[8 + k];
      ao += ek * Wo[8 + k];
      #pragma unroll
      for (int j = 0; j < H; ++j) ac[j] += ek * WC[(8 + k) * H + j];
    }
    float* ped = pe + d * 11 * TB;
    ped[0 * TB + r] = af;
    ped[1 * TB + r] = ai;
    ped[2 * TB + r] = ao;
    #pragma unroll
    for (int j = 0; j < H; ++j) ped[(3 + j) * TB + r] = ac[j];
  }
}

// ---------------- kernel 2: sequential LSTM; writes bf16 thbf[TB][32] directly -------
__global__ __launch_bounds__(64) void k_lstm(P1 p, const float* __restrict__ pe,
                                             ushort* __restrict__ thbf) {
  int dir = blockIdx.x;
  int lane = threadIdx.x;
  const float* Wf = dir ? p.Wf2 : p.Wf1;
  const float* Wi = dir ? p.Wi2 : p.Wi1;
  const float* Wo = dir ? p.Wo2 : p.Wo1;
  const float* WC = dir ? p.WC2 : p.WC1;
  float wf[8], wi[8], wo[8], wc[8][8];
  #pragma unroll
  for (int k = 0; k < 8; ++k) { wf[k] = Wf[k]; wi[k] = Wi[k]; wo[k] = Wo[k]; }
  #pragma unroll
  for (int k = 0; k < 8; ++k)
    #pragma unroll
    for (int j = 0; j < 8; ++j) wc[k][j] = WC[k * H + j];

  float h[8], C[8];
  #pragma unroll
  for (int j = 0; j < 8; ++j) { h[j] = 0.f; C[j] = 0.f; }

  const float* ped = pe + dir * 11 * TB;

  int tf = dir ? (T - 1) : 0;
  int rf = tf * B + lane;
  float nf = ped[0 * TB + rf], ni = ped[1 * TB + rf], no_ = ped[2 * TB + rf];
  float nc[8];
  #pragma unroll
  for (int j = 0; j < 8; ++j) nc[j] = ped[(3 + j) * TB + rf];

  ushort zed[8] = {0,0,0,0,0,0,0,0};

  for (int s = 0; s < T; ++s) {
    int t = dir ? (T - 1 - s) : s;
    int r = t * B + lane;
    float af = nf, ai = ni, ao = no_;
    float ac[8];
    #pragma unroll
    for (int j = 0; j < 8; ++j) ac[j] = nc[j];

    if (s + 1 < T) {
      int t2 = dir ? (T - 2 - s) : (s + 1);
      int r2 = t2 * B + lane;
      nf = ped[0 * TB + r2]; ni = ped[1 * TB + r2]; no_ = ped[2 * TB + r2];
      #pragma unroll
      for (int j = 0; j < 8; ++j) nc[j] = ped[(3 + j) * TB + r2];
    }

    ushort hb[8];
    #pragma unroll
    for (int j = 0; j < 8; ++j) hb[j] = f2bf(h[j]);
    *(bf16x8*)(thbf + (long)r * 32 + dir * 8)      = *(bf16x8*)hb;   // K halves
    *(bf16x8*)(thbf + (long)r * 32 + 16 + dir * 8) = *(bf16x8*)zed;  // zero pad

    #pragma unroll
    for (int k = 0; k < 8; ++k) {
      float hk = h[k];
      af += hk * wf[k];
      ai += hk * wi[k];
      ao += hk * wo[k];
      #pragma unroll
      for (int j = 0; j < 8; ++j) ac[j] += hk * wc[k][j];
    }
    float f = sigm_f(af), i = sigm_f(ai), o = sigm_f(ao);
    #pragma unroll
    for (int j = 0; j < 8; ++j) {
      float Cn = f * C[j] + i + tanh_f(ac[j]);
      C[j] = Cn;
      h[j] = o * tanh_f(Cn);
    }
  }
}

// ---------------- prep: Wout fp32 [16][V] -> Wbf bf16 [V][32] (K padded) ------------
__global__ __launch_bounds__(256) void k_cvtW(const float* __restrict__ Wout,
                                              ushort* __restrict__ Wbf) {
  int c = blockIdx.x * 256 + threadIdx.x;
  ushort tmp[32];
  #pragma unroll
  for (int k = 0; k < 16; ++k) tmp[k] = f2bf(Wout[k * V + c]);
  #pragma unroll
  for (int k = 16; k < 32; ++k) tmp[k] = 0;
  #pragma unroll
  for (int i = 0; i < 4; ++i)
    *(bf16x8*)(Wbf + (long)c * 32 + i * 8) = *(bf16x8*)(tmp + i * 8);
}

// ---------------- pass 1 (MFMA, swapped): per-slice sumexp ----------------
// A = W-tile (M dim = 16 cols), B = th (N dim = 16 rows).
// Lane l: row = l&15 (fixed), cols = (l>>4)*4+j. One scalar accumulator/lane.
// grid (NSL/4, TB/16); block = 4 waves, wave wv handles slice bIdx.x*4+wv.
__global__ __launch_bounds__(256) void k_sum(const ushort* __restrict__ thbf,
                                             const ushort* __restrict__ Wbf,
                                             const float* __restrict__ bout,
                                             float* __restrict__ pms) {
  int tid = threadIdx.x;
  int wv = tid >> 6, l = tid & 63;
  int r0 = blockIdx.y * 16;
  int slice = blockIdx.x * 4 + wv;
  int cbase = slice * (TPW * 16);
  int lr = l & 15, lq = l >> 4;

  bf16x8 Bt = *(const bf16x8*)(thbf + (long)(r0 + lr) * 32 + lq * 8);

  // software pipeline: prefetch t+1 W-frag
  bf16x8 Af = *(const bf16x8*)(Wbf + (long)(cbase + lr) * 32 + lq * 8);
  float4 bb = *(const float4*)(bout + cbase + lq * 4);

  float racc = 0.f;
  for (int t = 0; t < TPW; ++t) {
    bf16x8 Ac = Af; float4 bc = bb;
    if (t + 1 < TPW) {
      int ca = cbase + (t + 1) * 16;
      Af = *(const bf16x8*)(Wbf + (long)(ca + lr) * 32 + lq * 8);
      bb = *(const float4*)(bout + ca + lq * 4);
    }
    f32x4 acc = {0.f, 0.f, 0.f, 0.f};
    acc = __builtin_amdgcn_mfma_f32_16x16x32_bf16(Ac, Bt, acc, 0, 0, 0);
    racc += __expf(acc[0] + bc.x) + __expf(acc[1] + bc.y)
          + __expf(acc[2] + bc.z) + __expf(acc[3] + bc.w);
  }
  racc += __shfl_xor(racc, 16);
  racc += __shfl_xor(racc, 32);
  if (l < 16) pms[(long)(r0 + l) * NSL + slice] = racc;
}

// ---------------- Z = log(sum of partials) ----------------
__global__ __launch_bounds__(256) void k_reduce(const float* __restrict__ pms, float* __restrict__ Z) {
  int r = blockIdx.x * 256 + threadIdx.x;
  float s = 0.f;
  #pragma unroll
  for (int i = 0; i < NSL; ++i) s += pms[(long)r * NSL + i];
  Z[r] = logf(s);
}

// ---------------- pass 2 (MFMA, swapped): logits + b - Z -> out, float4 stores ------
__global__ __launch_bounds__(256) void k_wr(const ushort* __restrict__ thbf,
                                            const ushort* __restrict__ Wbf,
                                            const float* __restrict__ bout,
                                            const float* __restrict__ Z,
                                            float* __restrict__ out) {
  int tid = threadIdx.x;
  int wv = tid >> 6, l = tid & 63;
  int r0 = blockIdx.y * 16;
  int slice = blockIdx.x * 4 + wv;
  int cbase = slice * (TPW * 16);
  int lr = l & 15, lq = l >> 4;

  bf16x8 Bt = *(const bf16x8*)(thbf + (long)(r0 + lr) * 32 + lq * 8);
  float Zr_ = Z[r0 + lr];
  float* orow = out + (long)(r0 + lr) * V;

  bf16x8 Af = *(const bf16x8*)(Wbf + (long)(cbase + lr) * 32 + lq * 8);
  float4 bb = *(const float4*)(bout + cbase + lq * 4);

  for (int t = 0; t < TPW; ++t) {
    bf16x8 Ac = Af; float4 bc = bb;
    if (t + 1 < TPW) {
      int ca = cbase + (t + 1) * 16;
      Af = *(const bf16x8*)(Wbf + (long)(ca + lr) * 32 + lq * 8);
      bb = *(const float4*)(bout + ca + lq * 4);
    }
    f32x4 acc = {0.f, 0.f, 0.f, 0.f};
    acc = __builtin_amdgcn_mfma_f32_16x16x32_bf16(Ac, Bt, acc, 0, 0, 0);
    float4 o4;
    o4.x = acc[0] + bc.x - Zr_;
    o4.y = acc[1] + bc.y - Zr_;
    o4.z = acc[2] + bc.z - Zr_;
    o4.w = acc[3] + bc.w - Zr_;
    *(float4*)(orow + cbase + t * 16 + lq * 4) = o4;
  }
}

extern "C" void kernel_launch(void* const* d_in, const int* in_sizes, int n_in,
                              void* d_out, int out_size, void* d_ws, size_t ws_size,
                              hipStream_t stream) {
  (void)in_sizes; (void)n_in; (void)out_size; (void)ws_size;
  P1 p;
  p.x   = (const int*)  d_in[0];
  p.emb = (const float*)d_in[1];
  p.Wf1 = (const float*)d_in[2];  p.bf1 = (const float*)d_in[3];
  p.Wi1 = (const float*)d_in[4];  p.bi1 = (const float*)d_in[5];
  p.WC1 = (const float*)d_in[6];  p.bC1 = (const float*)d_in[7];
  p.Wo1 = (const float*)d_in[8];  p.bo1 = (const float*)d_in[9];
  p.Wf2 = (const float*)d_in[10]; p.bf2 = (const float*)d_in[11];
  p.Wi2 = (const float*)d_in[12]; p.bi2 = (const float*)d_in[13];
  p.WC2 = (const float*)d_in[14]; p.bC2 = (const float*)d_in[15];
  p.Wo2 = (const float*)d_in[16]; p.bo2 = (const float*)d_in[17];
  const float* Wout = (const float*)d_in[18];
  const float* bout = (const float*)d_in[19];

  float*  pe   = (float*)d_ws;                     // 180224 f
  float*  pms  = pe + 2 * 11 * TB;                 // TB*NSL = 327680 f
  float*  Zr   = pms + (long)TB * NSL;             // 8192 f
  ushort* thbf = (ushort*)(Zr + TB);               // TB*32 ushort
  ushort* Wbf  = thbf + (long)TB * 32;             // V*32 ushort

  float* out = (float*)d_out;

  k_embed <<<dim3(TB / 256),      dim3(256), 0, stream>>>(p, pe);
  k_cvtW  <<<dim3(V / 256),       dim3(256), 0, stream>>>(Wout, Wbf);
  k_lstm  <<<dim3(2),             dim3(64),  0, stream>>>(p, pe, thbf);
  k_sum   <<<dim3(NSL/4, TB/16),  dim3(256), 0, stream>>>(thbf, Wbf, bout, pms);
  k_reduce<<<dim3(TB / 256),      dim3(256), 0, stream>>>(pms, Zr);
  k_wr    <<<dim3(NSL/4, TB/16),  dim3(256), 0, stream>>>(thbf, Wbf, bout, Zr, out);
}